// Round 7
// baseline (941.943 us; speedup 1.0000x reference)
//
#include <hip/hip_runtime.h>

typedef _Float16 h2v __attribute__((ext_vector_type(2)));
typedef _Float16 h4v __attribute__((ext_vector_type(4)));
typedef _Float16 h8v __attribute__((ext_vector_type(8)));
typedef float    f4v __attribute__((ext_vector_type(4)));
typedef unsigned int u32;
typedef unsigned long long u64;

#define RSTRIDE 264                    // wup / G-bounce padded row: 528 B
#define PK_BYTES 131072                // packed b-frag matrix: 16nt*8kk*64lane*16B
#define P_OFF   135168                 // after G region 256*264*2
#define HS_OFF  137216
#define CS_OFF  137728
#define LDS_K2  138240
#define LDS_K1  32768                  // 2 x 16KB w-tile double buffer

__device__ inline f4v mfma16(h8v a, h8v b, f4v c) {
  return __builtin_amdgcn_mfma_f32_16x16x32_f16(a, b, c, 0, 0, 0);
}

__device__ inline float dot2f(u32 a, u32 b, float c) {
#if __has_builtin(__builtin_amdgcn_fdot2)
  return __builtin_amdgcn_fdot2(__builtin_bit_cast(h2v, a), __builtin_bit_cast(h2v, b), c, false);
#else
  h2v av = __builtin_bit_cast(h2v, a), bv = __builtin_bit_cast(h2v, b);
  return c + (float)av[0] * (float)bv[0] + (float)av[1] * (float)bv[1];
#endif
}

__device__ inline h8v cvt8(f4v lo, f4v hi) {
  h8v d;
  d[0] = (_Float16)lo[0]; d[1] = (_Float16)lo[1]; d[2] = (_Float16)lo[2]; d[3] = (_Float16)lo[3];
  d[4] = (_Float16)hi[0]; d[5] = (_Float16)hi[1]; d[6] = (_Float16)hi[2]; d[7] = (_Float16)hi[3];
  return d;
}

__device__ inline h8v cmb8(u64 lo, u64 hi) {
  h4v l4 = __builtin_bit_cast(h4v, lo), h4 = __builtin_bit_cast(h4v, hi);
  return __builtin_shufflevector(l4, h4, 0, 1, 2, 3, 4, 5, 6, 7);
}

__device__ inline void glds16(const void* g, void* l) {
  __builtin_amdgcn_global_load_lds(
      (const __attribute__((address_space(1))) unsigned int*)g,
      (__attribute__((address_space(3))) unsigned int*)l, 16, 0, 0);
}

// ---- prep: Wu padded row-major (for recurrence row pulls) ----
__global__ void prep_k(const float* __restrict__ Wu, _Float16* __restrict__ wup)
{
  int j = blockIdx.x, k = threadIdx.x;
  wup[j * RSTRIDE + k] = (_Float16)Wu[j * 256 + k];
  if (k < 8) wup[j * RSTRIDE + 256 + k] = (_Float16)0.f;
}

// ---- prep2: pack Wv / Ww into MFMA B-fragment order ----
// dst[((nt*8+kk)*64 + lane)*8 + h], lane=(l15,g):
//   k = kk*32 + (h<4 ? 4g+h : 16+4g+(h-4)),  j = nt*16+l15
//   wvp: Wv[k][j]   (B of GEMM1);  wwp: Ww[j][k]  (B of GEMM2)
__global__ void prep2_k(const float* __restrict__ Wv, const float* __restrict__ Ww,
                        _Float16* __restrict__ wvp, _Float16* __restrict__ wwp)
{
  int b = blockIdx.x;
  int mat = b >> 7, ntkk = b & 127;
  int tid = threadIdx.x;
  int lane = tid & 63, q = tid >> 6;
  int g2 = (lane >> 4) & 3, l15 = lane & 15;
  int nt = ntkk >> 3, kk = ntkk & 7;
  int j = nt * 16 + l15;
  _Float16* dst = (mat == 0 ? wvp : wwp) + ((size_t)(ntkk * 64 + lane)) * 8;
#pragma unroll
  for (int e = 0; e < 2; ++e) {
    int h = 2 * q + e;
    int k = kk * 32 + (h < 4 ? 4 * g2 + h : 16 + 4 * g2 + (h - 4));
    float val = (mat == 0) ? Wv[(size_t)k * 256 + j] : Ww[(size_t)j * 256 + k];
    dst[h] = (_Float16)val;
  }
}

// out[b,i] = sum_j M[i,j] * V[b,j]   (beta = Ww@b ; final x = Wv@c)
__global__ void matvec_k(const float* __restrict__ M, const float* __restrict__ V,
                         float* __restrict__ out)
{
  __shared__ float vb[256];
  int b = blockIdx.x, i = threadIdx.x;
  vb[i] = V[(size_t)b * 256 + i];
  __syncthreads();
  float a0 = 0.f;
#pragma unroll 8
  for (int j = 0; j < 256; j += 4) {
    f4v m = *(const f4v*)(M + (size_t)i * 256 + j);
    a0 += m[0] * vb[j] + m[1] * vb[j + 1] + m[2] * vb[j + 2] + m[3] * vb[j + 3];
  }
  out[(size_t)b * 256 + i] = a0;
}

// ---------------- K1: Tt[b,j,t] = sum_k w[b,t,k] * Wv[k,j] ----------------
// 2 blocks per batch (t-rows split). w staged via global_load_lds into
// [8 chunks][128 rows]x16B tiles; counted-vmcnt double-buffer pipeline.
#define STAGE1(bufi, kki) { \
    _Pragma("unroll") \
    for (int i_ = 0; i_ < 2; ++i_) { \
      int idx_ = i_ * 512 + tid; \
      int c_ = idx_ >> 7, r_ = idx_ & 127; \
      glds16(wbh + r_ * 256 + (kki) * 32 + c_ * 4, \
             smem + (bufi) * 16384 + idx_ * 16); \
    } }

__global__ __launch_bounds__(512, 4) void gemm1_k(
    const float* __restrict__ w, const _Float16* __restrict__ wvp,
    _Float16* __restrict__ TG)
{
  extern __shared__ char smem[];
  const int tid = threadIdx.x;
  const int wv = tid >> 6, lane = tid & 63, g = (lane >> 4) & 3, l15 = lane & 15;
  const int bid = blockIdx.x;
  const int B = bid >> 1, half = bid & 1;
  const float* wbh = w + (size_t)B * 65536 + half * 32768;

  f4v acc[16];
#pragma unroll
  for (int nt = 0; nt < 16; ++nt) acc[nt] = f4v{0.f, 0.f, 0.f, 0.f};

  STAGE1(0, 0);
  STAGE1(1, 1);

  const int r0 = wv * 16 + l15;
  const h8v* bfbase = (const h8v*)wvp;

#pragma unroll
  for (int kk = 0; kk < 8; ++kk) {
    if (kk < 7) { asm volatile("s_waitcnt vmcnt(2)" ::: "memory"); }
    else        { asm volatile("s_waitcnt vmcnt(0)" ::: "memory"); }
    __builtin_amdgcn_s_barrier();
    asm volatile("" ::: "memory");

    const char* tb = smem + (kk & 1) * 16384;
    f4v al = *(const f4v*)(tb + g * 2048 + r0 * 16);
    f4v ah = *(const f4v*)(tb + (g + 4) * 2048 + r0 * 16);
    h8v a0 = cvt8(al, ah);

    const h8v* bfp = bfbase + kk * 64 + lane;
#pragma unroll
    for (int nt = 0; nt < 16; ++nt) {
      h8v bf = bfp[nt * 512];
      acc[nt] = mfma16(a0, bf, acc[nt]);
    }

    asm volatile("" ::: "memory");
    __builtin_amdgcn_s_barrier();
    asm volatile("" ::: "memory");
    if (kk < 6) { STAGE1(kk & 1, kk + 2); }
  }

  // epilogue: Tt[b, j=n, t=m]; cached stores, line filled by wave pairs
  _Float16* out = TG + (size_t)B * 65536;
  const int m0 = half * 128 + wv * 16 + g * 4;
#pragma unroll
  for (int nt = 0; nt < 16; ++nt) {
    int n = nt * 16 + l15;
    f4v a = acc[nt];
    h4v t4; t4[0] = (_Float16)a[0]; t4[1] = (_Float16)a[1];
    t4[2] = (_Float16)a[2]; t4[3] = (_Float16)a[3];
    *(h4v*)(out + (size_t)n * 256 + m0) = t4;
  }
}

// ---------- K2 fused: G = Ww @ T (A=Tt via glds pipeline) + recurrence -----
#define STAGE2(bufi, kki) { \
    _Pragma("unroll") \
    for (int i_ = 0; i_ < 2; ++i_) { \
      int idx_ = i_ * 512 + tid; \
      int c_ = idx_ >> 8, r_ = idx_ & 255; \
      glds16(Tb + r_ * 256 + (kki) * 32 + c_ * 8, \
             smem + (bufi) * 16384 + idx_ * 16); \
    } }

__global__ __launch_bounds__(512, 1) void g_recur_k(
    const _Float16* __restrict__ TG, const _Float16* __restrict__ wwp,
    const _Float16* __restrict__ wup, const float* __restrict__ beta,
    float* __restrict__ cout)
{
  extern __shared__ char smem[];
  _Float16* reg = (_Float16*)smem;                 // staging dbuf, then G bounce
  float*    P   = (float*)(smem + P_OFF);
  _Float16* HS  = (_Float16*)(smem + HS_OFF);
  _Float16* CS  = (_Float16*)(smem + CS_OFF);

  const int tid = threadIdx.x;
  const int wv = tid >> 6, lane = tid & 63, g = (lane >> 4) & 3, l15 = lane & 15;
  const int B = blockIdx.x;
  const _Float16* Tb = TG + (size_t)B * 65536;

  f4v acc[2][16];
#pragma unroll
  for (int mt = 0; mt < 2; ++mt)
#pragma unroll
    for (int nt = 0; nt < 16; ++nt) acc[mt][nt] = f4v{0.f, 0.f, 0.f, 0.f};

  STAGE2(0, 0);
  STAGE2(1, 1);

  const int r0 = wv * 32 + l15, r1 = r0 + 16;
  const h8v* bfbase = (const h8v*)wwp;

  // GEMM2: C[j,i] = sum_t Tt[b,j,t] * Ww[i,t]  ( = G[i,j] )
#pragma unroll
  for (int kk = 0; kk < 8; ++kk) {
    if (kk < 7) { asm volatile("s_waitcnt vmcnt(2)" ::: "memory"); }
    else        { asm volatile("s_waitcnt vmcnt(0)" ::: "memory"); }
    __builtin_amdgcn_s_barrier();
    asm volatile("" ::: "memory");

    const char* tb = smem + (kk & 1) * 16384;
    const int co = (g >> 1) * 4096 + 8 * (g & 1);
    u64 lo0 = *(const u64*)(tb + co + r0 * 16);
    u64 hi0 = *(const u64*)(tb + co + 8192 + r0 * 16);
    u64 lo1 = *(const u64*)(tb + co + r1 * 16);
    u64 hi1 = *(const u64*)(tb + co + 8192 + r1 * 16);
    h8v a0 = cmb8(lo0, hi0);
    h8v a1 = cmb8(lo1, hi1);

    const h8v* bfp = bfbase + kk * 64 + lane;
#pragma unroll
    for (int nt = 0; nt < 16; ++nt) {
      h8v bf = bfp[nt * 512];
      acc[0][nt] = mfma16(a0, bf, acc[0][nt]);
      acc[1][nt] = mfma16(a1, bf, acc[1][nt]);
    }

    asm volatile("" ::: "memory");
    __builtin_amdgcn_s_barrier();
    asm volatile("" ::: "memory");
    if (kk < 6) { STAGE2(kk & 1, kk + 2); }
  }
  __syncthreads();   // staging region about to be overwritten by G bounce

  // bounce G[i=n][j=m] into LDS
#pragma unroll
  for (int mt = 0; mt < 2; ++mt)
#pragma unroll
    for (int nt = 0; nt < 16; ++nt) {
      int n = nt * 16 + l15;
      int m0 = wv * 32 + mt * 16 + g * 4;
      f4v a = acc[mt][nt];
      h4v t4; t4[0] = (_Float16)a[0]; t4[1] = (_Float16)a[1];
      t4[2] = (_Float16)a[2]; t4[3] = (_Float16)a[3];
      *(h4v*)(reg + n * RSTRIDE + m0) = t4;
    }
  __syncthreads();

  // pull my half-row of G into registers; Wu half-row from global (L2-hot)
  const int i  = tid & 255;
  const int h2 = tid >> 8;
  uint4 gq[16], wq[16];
#pragma unroll
  for (int q = 0; q < 16; ++q)
    gq[q] = *(const uint4*)(smem + i * 528 + h2 * 256 + q * 16);
  {
    const uint4* wrow = (const uint4*)(wup + (size_t)i * RSTRIDE) + h2 * 16;
#pragma unroll
    for (int q = 0; q < 16; ++q) wq[q] = wrow[q];
  }
  float my_beta = beta[(size_t)B * 256 + i];

  if (tid < 256) HS[tid] = (_Float16)0.f; else CS[tid - 256] = (_Float16)0.f;
  float cm = 0.f;
  __syncthreads();

  const uint4* hrow = (const uint4*)((const char*)HS + h2 * 256);
  const uint4* crow = (const uint4*)((const char*)CS + h2 * 256);

  for (int t = 0; t < 20; ++t) {
    float au[4] = {0.f, 0.f, 0.f, 0.f};
    float ag[4] = {0.f, 0.f, 0.f, 0.f};
#pragma unroll
    for (int q = 0; q < 16; ++q) {
      uint4 wu4 = wq[q];
      uint4 gg  = gq[q];
      uint4 hv  = hrow[q];
      uint4 cv  = crow[q];
      float a = au[q & 3], e = ag[q & 3];
      a = dot2f(wu4.x, hv.x, a);
      a = dot2f(wu4.y, hv.y, a);
      a = dot2f(wu4.z, hv.z, a);
      a = dot2f(wu4.w, hv.w, a);
      e = dot2f(gg.x, cv.x, e);
      e = dot2f(gg.y, cv.y, e);
      e = dot2f(gg.z, cv.z, e);
      e = dot2f(gg.w, cv.w, e);
      au[q & 3] = a; ag[q & 3] = e;
    }
    float auf = (au[0] + au[1]) + (au[2] + au[3]);
    float agf = (ag[0] + ag[1]) + (ag[2] + ag[3]);
    P[tid] = (auf - agf) * 128.f;   // descale 2^7
    __syncthreads();
    float y = my_beta + P[i] + P[i + 256];
    float hval = fmaxf(y, 0.f);
    if (h2 == 0) {
      cm += hval;
      HS[i] = (_Float16)(hval * 0.0078125f);  // * 2^-7
      CS[i] = (_Float16)(cm * 0.0078125f);
    }
    __syncthreads();
  }
  if (h2 == 0) cout[(size_t)B * 256 + i] = cm;
}

extern "C" void kernel_launch(void* const* d_in, const int* in_sizes, int n_in,
                              void* d_out, int out_size, void* d_ws, size_t ws_size,
                              hipStream_t stream)
{
  const float* w  = (const float*)d_in[0];
  const float* b  = (const float*)d_in[1];
  const float* Ww = (const float*)d_in[2];
  const float* Wu = (const float*)d_in[3];
  const float* Wv = (const float*)d_in[4];

  char* ws = (char*)d_ws;
  float*    beta = (float*)(ws);
  float*    cbuf = (float*)(ws + (size_t)2 * 1024 * 1024);
  _Float16* wvp  = (_Float16*)(ws + (size_t)4 * 1024 * 1024);
  _Float16* wwp  = (_Float16*)(ws + (size_t)4 * 1024 * 1024 + PK_BYTES);
  _Float16* wup  = (_Float16*)(ws + (size_t)4 * 1024 * 1024 + 2 * (size_t)PK_BYTES);
  _Float16* TG   = (_Float16*)(ws + (size_t)8 * 1024 * 1024);

  (void)in_sizes; (void)n_in; (void)out_size; (void)ws_size;

  hipFuncSetAttribute((const void*)gemm1_k,
                      hipFuncAttributeMaxDynamicSharedMemorySize, LDS_K1);
  hipFuncSetAttribute((const void*)g_recur_k,
                      hipFuncAttributeMaxDynamicSharedMemorySize, LDS_K2);

  prep_k<<<256, 256, 0, stream>>>(Wu, wup);
  prep2_k<<<256, 256, 0, stream>>>(Wv, Ww, wvp, wwp);
  matvec_k<<<2048, 256, 0, stream>>>(Ww, b, beta);                    // beta = Ww @ b
  gemm1_k<<<4096, 512, LDS_K1, stream>>>(w, wvp, TG);                 // Tt = (w_b @ Wv)^T
  g_recur_k<<<2048, 512, LDS_K2, stream>>>(TG, wwp, wup, beta, cbuf); // G + recurrence
  matvec_k<<<2048, 256, 0, stream>>>(Wv, cbuf, (float*)d_out);        // x = Wv @ c
}

// Round 8
// 678.146 us; speedup vs baseline: 1.3890x; 1.3890x over previous
//
#include <hip/hip_runtime.h>

typedef _Float16 h2v __attribute__((ext_vector_type(2)));
typedef _Float16 h4v __attribute__((ext_vector_type(4)));
typedef _Float16 h8v __attribute__((ext_vector_type(8)));
typedef float    f4v __attribute__((ext_vector_type(4)));
typedef unsigned int u32;
typedef unsigned long long u64;

#define WUP_STRIDE 264        // wup padded row (halves)
#define NBATCH 2

// LDS layout (bytes) for fused_k
#define WT_STRIDE 264         // halves per w-tile row (528 B: 2-way banks, free)
#define WT0_OFF   0
#define WT1_OFF   16896       // 32*264*2
#define TT_OFF    33792
#define TT_STRIDE 36          // halves per Tt row (72 B)
#define GC_STRIDE 268         // halves per G-chunk row (536 B, 8-B aligned rows)
#define WWS0_OFF  52224       // 33792 + 18432
#define WWS1_OFF  68608
#define P_OFF     84992
#define HS_OFF    87040
#define CS_OFF    87552
#define LDS_FUSED 88064

__device__ inline f4v mfma16(h8v a, h8v b, f4v c) {
  return __builtin_amdgcn_mfma_f32_16x16x32_f16(a, b, c, 0, 0, 0);
}

__device__ inline float dot2f(u32 a, u32 b, float c) {
#if __has_builtin(__builtin_amdgcn_fdot2)
  return __builtin_amdgcn_fdot2(__builtin_bit_cast(h2v, a), __builtin_bit_cast(h2v, b), c, false);
#else
  h2v av = __builtin_bit_cast(h2v, a), bv = __builtin_bit_cast(h2v, b);
  return c + (float)av[0] * (float)bv[0] + (float)av[1] * (float)bv[1];
#endif
}

__device__ inline h8v cvt8(f4v lo, f4v hi) {
  h8v d;
  d[0] = (_Float16)lo[0]; d[1] = (_Float16)lo[1]; d[2] = (_Float16)lo[2]; d[3] = (_Float16)lo[3];
  d[4] = (_Float16)hi[0]; d[5] = (_Float16)hi[1]; d[6] = (_Float16)hi[2]; d[7] = (_Float16)hi[3];
  return d;
}

// raw barrier: LDS-visibility only, never drains vmcnt (keeps prefetch alive)
#define BAR() { asm volatile("s_waitcnt lgkmcnt(0)" ::: "memory"); \
                __builtin_amdgcn_s_barrier(); \
                asm volatile("" ::: "memory"); }

// fragment loader: ROW-BASE pointer; kk/g offsets applied exactly once
#define LDH(basep, kk, dst) { \
    h4v lo_ = *(const h4v*)((basep) + (kk)*32 + 4*g); \
    h4v hi_ = *(const h4v*)((basep) + (kk)*32 + 16 + 4*g); \
    dst = __builtin_shufflevector(lo_, hi_, 0, 1, 2, 3, 4, 5, 6, 7); }

// ---- prep: Wu padded row-major (for recurrence row pulls) ----
__global__ void prep_k(const float* __restrict__ Wu, _Float16* __restrict__ wup)
{
  int j = blockIdx.x, k = threadIdx.x;
  wup[j * WUP_STRIDE + k] = (_Float16)Wu[j * 256 + k];
  if (k < 8) wup[j * WUP_STRIDE + 256 + k] = (_Float16)0.f;
}

// ---- prep2: pack Wv (wvp, k-contraction frags) and Ww (wwp2, t-sliced frags)
// koff(g,h) = h<4 ? 4g+h : 16+4g+(h-4)
// wvp [(nt*8+kk)*64+lane]*8+h  = Wv[kk*32+koff][nt*16+l15]
// wwp2[(tau*16+it)*64+lane]*8+h = Ww[it*16+l15][tau*32+koff]
__global__ void prep2_k(const float* __restrict__ Wv, const float* __restrict__ Ww,
                        _Float16* __restrict__ wvp, _Float16* __restrict__ wwp2)
{
  int b = blockIdx.x;
  int tid = threadIdx.x;
  int lane = tid & 63, q = tid >> 6;
  int g2 = (lane >> 4) & 3, l15 = lane & 15;
  if (b < 128) {
    int nt = b >> 3, kk = b & 7;
    int j = nt * 16 + l15;
    _Float16* dst = wvp + ((size_t)(b * 64 + lane)) * 8;
#pragma unroll
    for (int e = 0; e < 2; ++e) {
      int h = 2 * q + e;
      int k = kk * 32 + (h < 4 ? 4 * g2 + h : 16 + 4 * g2 + (h - 4));
      dst[h] = (_Float16)Wv[(size_t)k * 256 + j];
    }
  } else {
    int s = b - 128;                 // tau*16 + it
    int it = s & 15;
    int tau = s >> 4;
    int i = it * 16 + l15;
    _Float16* dst = wwp2 + ((size_t)(s * 64 + lane)) * 8;
#pragma unroll
    for (int e = 0; e < 2; ++e) {
      int h = 2 * q + e;
      int t = tau * 32 + (h < 4 ? 4 * g2 + h : 16 + 4 * g2 + (h - 4));
      dst[h] = (_Float16)Ww[(size_t)i * 256 + t];
    }
  }
}

// out[b,i] = sum_j M[i,j] * V[b,j]   (beta = Ww@b ; final x = Wv@c)
__global__ void matvec_k(const float* __restrict__ M, const float* __restrict__ V,
                         float* __restrict__ out)
{
  __shared__ float vb[256];
  int b = blockIdx.x, i = threadIdx.x;
  vb[i] = V[(size_t)b * 256 + i];
  __syncthreads();
  float a0 = 0.f;
#pragma unroll 8
  for (int j = 0; j < 256; j += 4) {
    f4v m = *(const f4v*)(M + (size_t)i * 256 + j);
    a0 += m[0] * vb[j] + m[1] * vb[j + 1] + m[2] * vb[j + 2] + m[3] * vb[j + 3];
  }
  out[(size_t)b * 256 + i] = a0;
}

// ================= fused: T-tile streaming + G accumulation + recurrence ====
// Per batch: for tau=0..7 (32 t-rows each):
//   GEMM1: T[tau,:]  (A = w rows from LDS tile, B = wvp from L2)  -> Tt LDS
//   GEMM2: G += Ww[:,tau] @ T[tau,:]  (A = Tt LDS, B = wwp2 LDS-staged) -> acc2
// Then G-bounce (8 chunks through Tt region) + 20-step recurrence.
__global__ __launch_bounds__(512, 2) void fused_k(
    const float* __restrict__ w, const _Float16* __restrict__ wvp,
    const _Float16* __restrict__ wwp2, const _Float16* __restrict__ wup,
    const float* __restrict__ beta, float* __restrict__ cout)
{
  extern __shared__ char smem[];
  _Float16* const TT = (_Float16*)(smem + TT_OFF);
  float*    const P  = (float*)(smem + P_OFF);
  _Float16* const HS = (_Float16*)(smem + HS_OFF);
  _Float16* const CS = (_Float16*)(smem + CS_OFF);

  const int tid = threadIdx.x;
  const int wv = tid >> 6, lane = tid & 63;
  const int g = (lane >> 4) & 3, l15 = lane & 15;
  const int st_t = tid >> 4;            // staging row 0..31
  const int st_c = (tid & 15) << 4;     // staging col base (floats/halves)
  const int i_r = tid & 255;            // recurrence row
  const int h2  = tid >> 8;

  f4v  sw[4];                           // staged w (next tile)
  uint4 sws0, sws1;                     // staged wwp2 (next slice)

  for (int bi = 0; bi < NBATCH; ++bi) {
    const int B = blockIdx.x * NBATCH + bi;
    const float* wb = w + (size_t)B * 65536;
    const int Bn = (B + 1 < 2048) ? (B + 1) : B;
    const float* wbn = w + (size_t)Bn * 65536;

    if (bi == 0) {
      // prologue: tile0 -> wtile[0]; wws slice0 -> wws[0]; stage tile1/slice1 regs
      const float* src0 = wb + st_t * 256 + st_c;
#pragma unroll
      for (int q = 0; q < 4; ++q) sw[q] = *(const f4v*)(src0 + q * 4);
      {
        _Float16* dst = (_Float16*)(smem + WT0_OFF) + st_t * WT_STRIDE + st_c;
        *(h8v*)dst = cvt8(sw[0], sw[1]);
        *(h8v*)(dst + 8) = cvt8(sw[2], sw[3]);
      }
      {
        const char* wsrc = (const char*)wwp2 + tid * 32;
        uint4 a = *(const uint4*)wsrc;
        uint4 c = *(const uint4*)(wsrc + 16);
        *(uint4*)(smem + WWS0_OFF + tid * 32) = a;
        *(uint4*)(smem + WWS0_OFF + tid * 32 + 16) = c;
      }
      const float* src1 = wb + (32 + st_t) * 256 + st_c;
#pragma unroll
      for (int q = 0; q < 4; ++q) sw[q] = *(const f4v*)(src1 + q * 4);
      {
        const char* wsrc = (const char*)wwp2 + 16384 + tid * 32;
        sws0 = *(const uint4*)wsrc;
        sws1 = *(const uint4*)(wsrc + 16);
      }
      BAR();
    }

    f4v acc2[2][16];
#pragma unroll
    for (int jt = 0; jt < 2; ++jt)
#pragma unroll
      for (int it = 0; it < 16; ++it) acc2[jt][it] = f4v{0.f, 0.f, 0.f, 0.f};

#pragma unroll 2
    for (int tau = 0; tau < 8; ++tau) {
      // ---- step1: GEMM1(tau): T[t,j] fragments ----
      f4v acc1[2][2];
#pragma unroll
      for (int a = 0; a < 2; ++a)
#pragma unroll
        for (int b2 = 0; b2 < 2; ++b2) acc1[a][b2] = f4v{0.f, 0.f, 0.f, 0.f};
      {
        const _Float16* wt = (const _Float16*)(smem + ((tau & 1) ? WT1_OFF : WT0_OFF));
#pragma unroll
        for (int kk = 0; kk < 8; ++kk) {
          h8v a0, a1;
          LDH(wt + (l15) * WT_STRIDE, kk, a0);            // t-tile rows 0..15
          LDH(wt + (16 + l15) * WT_STRIDE, kk, a1);       // rows 16..31
#pragma unroll
          for (int jn = 0; jn < 2; ++jn) {
            const int JN = wv * 2 + jn;
            h8v bf = *(const h8v*)(wvp + ((size_t)(JN * 8 + kk) * 64 + lane) * 8);
            acc1[0][jn] = mfma16(a0, bf, acc1[0][jn]);
            acc1[1][jn] = mfma16(a1, bf, acc1[1][jn]);
          }
        }
      }
      // ---- step2: write wtile[(tau+1)&1] from staged regs; issue next w loads
      {
        _Float16* dst = (_Float16*)(smem + (((tau + 1) & 1) ? WT1_OFF : WT0_OFF))
                        + st_t * WT_STRIDE + st_c;
        *(h8v*)dst = cvt8(sw[0], sw[1]);
        *(h8v*)(dst + 8) = cvt8(sw[2], sw[3]);
      }
      {
        const int tld = tau + 2;
        const float* src = (tld <= 7)
            ? (wb  + (size_t)(tld * 32 + st_t) * 256 + st_c)
            : (wbn + (size_t)((tld - 8) * 32 + st_t) * 256 + st_c);
#pragma unroll
        for (int q = 0; q < 4; ++q) sw[q] = *(const f4v*)(src + q * 4);
      }
      // ---- step3 ----
      BAR();
      // ---- step4: write Tt(tau); write wws[(tau+1)&1]; issue next wws loads
#pragma unroll
      for (int tm = 0; tm < 2; ++tm)
#pragma unroll
        for (int jn = 0; jn < 2; ++jn) {
          const int j = wv * 32 + jn * 16 + l15;
          f4v a = acc1[tm][jn];
          h4v t4; t4[0] = (_Float16)a[0]; t4[1] = (_Float16)a[1];
          t4[2] = (_Float16)a[2]; t4[3] = (_Float16)a[3];
          *(h4v*)(TT + j * TT_STRIDE + tm * 16 + g * 4) = t4;
        }
      {
        char* wdst = smem + (((tau + 1) & 1) ? WWS1_OFF : WWS0_OFF) + tid * 32;
        *(uint4*)wdst = sws0;
        *(uint4*)(wdst + 16) = sws1;
        const char* wsrc = (const char*)wwp2 + (size_t)((tau + 2) & 7) * 16384 + tid * 32;
        sws0 = *(const uint4*)wsrc;
        sws1 = *(const uint4*)(wsrc + 16);
      }
      // ---- step5 ----
      BAR();
      // ---- step6: GEMM2(tau): G[j-fragments][i] += Tt * Ww ----
      {
        const char* wws = smem + ((tau & 1) ? WWS1_OFF : WWS0_OFF);
        h8v a0, a1;
        LDH(TT + (wv * 32 + l15) * TT_STRIDE, 0, a0);
        LDH(TT + (wv * 32 + 16 + l15) * TT_STRIDE, 0, a1);
#pragma unroll
        for (int it = 0; it < 16; ++it) {
          h8v bf = *(const h8v*)(wws + (it * 64 + lane) * 16);
          acc2[0][it] = mfma16(a0, bf, acc2[0][it]);
          acc2[1][it] = mfma16(a1, bf, acc2[1][it]);
        }
      }
    } // tau

    BAR();   // TT free -> reuse as G-chunk buffer

    // ---- G bounce: 8 chunks of 32 i-rows through TT region ----
    uint4 gq[16];
    _Float16* const GC = TT;   // stride GC_STRIDE halves
#pragma unroll
    for (int c = 0; c < 8; ++c) {
#pragma unroll
      for (int jt = 0; jt < 2; ++jt)
#pragma unroll
        for (int e = 0; e < 2; ++e) {
          const int IT = 2 * c + e;
          const int il = e * 16 + l15;                 // i - c*32
          const int j  = wv * 32 + jt * 16 + g * 4;
          f4v a = acc2[jt][IT];
          h4v t4; t4[0] = (_Float16)a[0]; t4[1] = (_Float16)a[1];
          t4[2] = (_Float16)a[2]; t4[3] = (_Float16)a[3];
          *(h4v*)(GC + il * GC_STRIDE + j) = t4;       // row il, cols j..j+3
        }
      BAR();
      if ((i_r >> 5) == c) {
        const int il = i_r & 31;
        const char* row = (const char*)(GC + il * GC_STRIDE) + h2 * 256;
#pragma unroll
        for (int q = 0; q < 16; ++q) {
          u64 lo = *(const u64*)(row + q * 16);
          u64 hi = *(const u64*)(row + q * 16 + 8);
          uint4 v;
          ((u64*)&v)[0] = lo; ((u64*)&v)[1] = hi;
          gq[q] = v;
        }
      }
      BAR();
    }

    // ---- recurrence (proven structure) ----
    uint4 wq[16];
    {
      const uint4* wrow = (const uint4*)(wup + (size_t)i_r * WUP_STRIDE) + h2 * 16;
#pragma unroll
      for (int q = 0; q < 16; ++q) wq[q] = wrow[q];
    }
    float my_beta = beta[(size_t)B * 256 + i_r];

    if (tid < 256) HS[tid] = (_Float16)0.f; else CS[tid - 256] = (_Float16)0.f;
    float cm = 0.f;
    BAR();

    const uint4* hrow = (const uint4*)((const char*)HS + h2 * 256);
    const uint4* crow = (const uint4*)((const char*)CS + h2 * 256);

    for (int t = 0; t < 20; ++t) {
      float au[4] = {0.f, 0.f, 0.f, 0.f};
      float ag[4] = {0.f, 0.f, 0.f, 0.f};
#pragma unroll
      for (int q = 0; q < 16; ++q) {
        uint4 wu4 = wq[q];
        uint4 gg  = gq[q];
        uint4 hv  = hrow[q];
        uint4 cv  = crow[q];
        float a = au[q & 3], e = ag[q & 3];
        a = dot2f(wu4.x, hv.x, a);
        a = dot2f(wu4.y, hv.y, a);
        a = dot2f(wu4.z, hv.z, a);
        a = dot2f(wu4.w, hv.w, a);
        e = dot2f(gg.x, cv.x, e);
        e = dot2f(gg.y, cv.y, e);
        e = dot2f(gg.z, cv.z, e);
        e = dot2f(gg.w, cv.w, e);
        au[q & 3] = a; ag[q & 3] = e;
      }
      float auf = (au[0] + au[1]) + (au[2] + au[3]);
      float agf = (ag[0] + ag[1]) + (ag[2] + ag[3]);
      P[tid] = (auf - agf) * 128.f;   // descale 2^7
      BAR();
      float y = my_beta + P[i_r] + P[i_r + 256];
      float hval = fmaxf(y, 0.f);
      if (h2 == 0) {
        cm += hval;
        HS[i_r] = (_Float16)(hval * 0.0078125f);  // * 2^-7
        CS[i_r] = (_Float16)(cm * 0.0078125f);
      }
      BAR();
    }
    if (h2 == 0) cout[(size_t)B * 256 + i_r] = cm;
    BAR();   // protect LDS before next batch
  } // bi
}

extern "C" void kernel_launch(void* const* d_in, const int* in_sizes, int n_in,
                              void* d_out, int out_size, void* d_ws, size_t ws_size,
                              hipStream_t stream)
{
  const float* w  = (const float*)d_in[0];
  const float* b  = (const float*)d_in[1];
  const float* Ww = (const float*)d_in[2];
  const float* Wu = (const float*)d_in[3];
  const float* Wv = (const float*)d_in[4];

  char* ws = (char*)d_ws;
  float*    beta = (float*)(ws);
  float*    cbuf = (float*)(ws + (size_t)2 * 1024 * 1024);
  _Float16* wvp  = (_Float16*)(ws + (size_t)4 * 1024 * 1024);
  _Float16* wwp2 = (_Float16*)(ws + (size_t)4 * 1024 * 1024 + 131072);
  _Float16* wup  = (_Float16*)(ws + (size_t)4 * 1024 * 1024 + 262144);

  (void)in_sizes; (void)n_in; (void)out_size; (void)ws_size;

  hipFuncSetAttribute((const void*)fused_k,
                      hipFuncAttributeMaxDynamicSharedMemorySize, LDS_FUSED);

  prep_k<<<256, 256, 0, stream>>>(Wu, wup);
  prep2_k<<<256, 256, 0, stream>>>(Wv, Ww, wvp, wwp2);
  matvec_k<<<2048, 256, 0, stream>>>(Ww, b, beta);                  // beta = Ww @ b
  fused_k<<<1024, 512, LDS_FUSED, stream>>>(w, wvp, wwp2, wup, beta, cbuf);
  matvec_k<<<2048, 256, 0, stream>>>(Wv, cbuf, (float*)d_out);      // x = Wv @ c
}